// Round 1
// baseline (394.545 us; speedup 1.0000x reference)
//
#include <hip/hip_runtime.h>
#include <stdint.h>

typedef __bf16 bf16x8 __attribute__((ext_vector_type(8)));
typedef float f32x4 __attribute__((ext_vector_type(4)));
typedef unsigned short u16;
typedef unsigned int u32;

#define N_INST 50000
#define NPAD   50048   // 391 * 128
#define LIN    1024
#define D1     512
#define D2     256
#define TOPK   64
#define TDIM   49

__device__ __forceinline__ float b2f(u16 u) {
    union { float f; u32 i; } x; x.i = ((u32)u) << 16; return x.f;
}
__device__ __forceinline__ u16 f2b(float f) {
    union { float f; u32 i; } x; x.f = f;
    u32 r = x.i + 0x7FFFu + ((x.i >> 16) & 1u);   // RNE
    return (u16)(r >> 16);
}

// ---------------- pack: W_fc -> WfcT bf16 [512][1024]; Wa/Wb -> WaT/WbT bf16 [256][512]
__global__ void pack_weights(const float* __restrict__ W_fc, const float* __restrict__ Wa,
                             const float* __restrict__ Wb, u16* __restrict__ WfcT,
                             u16* __restrict__ WaT, u16* __restrict__ WbT) {
    int e = blockIdx.x * blockDim.x + threadIdx.x;
    if (e < D1 * LIN) {
        int n = e >> 10, k = e & 1023;
        WfcT[e] = f2b(W_fc[(size_t)k * D1 + n]);
    }
    int f = e - D1 * LIN;
    if (f >= 0 && f < D2 * D1) {
        int j = f >> 9, k = f & 511;
        WaT[f] = f2b(Wa[(size_t)k * D2 + j]);
        WbT[f] = f2b(Wb[(size_t)k * D2 + j]);
    }
}

// ---------------- GEMM1: h512 = relu(h @ W_fc + b_fc), bf16 out. tile 128x256, 8 waves.
__global__ __launch_bounds__(512, 2)
void gemm_fc(const float* __restrict__ h, const u16* __restrict__ WfcT,
             const float* __restrict__ b_fc, u16* __restrict__ h512) {
    __shared__ __align__(16) u16 lA[128 * 64];
    __shared__ __align__(16) u16 lB[256 * 64];
    const int tid = threadIdx.x;
    const int lane = tid & 63, wid = tid >> 6;
    const int wr = wid >> 2, wc = wid & 3;          // 2 x 4 wave grid
    const int lanelo = lane & 15, lanehi = lane >> 4;
    const int row0 = blockIdx.y * 128;
    const int col0 = blockIdx.x * 256;

    f32x4 acc[4][4];
    const f32x4 z4 = {0.f, 0.f, 0.f, 0.f};
    for (int m = 0; m < 4; ++m)
        for (int n = 0; n < 4; ++n) acc[m][n] = z4;

    for (int kt = 0; kt < LIN / 64; ++kt) {
        // stage A: 128 rows x 64 k, fp32 -> bf16, XOR-swizzled LDS
        #pragma unroll
        for (int q = 0; q < 4; ++q) {
            int idx = tid + 512 * q;
            int row = idx >> 4, k4 = idx & 15;
            int srow = row0 + row; if (srow >= N_INST) srow = N_INST - 1;
            const float4 v = *(const float4*)(h + (size_t)srow * LIN + kt * 64 + k4 * 4);
            ushort4 b; b.x = f2b(v.x); b.y = f2b(v.y); b.z = f2b(v.z); b.w = f2b(v.w);
            u32 off = row * 128 + ((k4 * 8) ^ ((row & 7) << 4));
            *(ushort4*)((char*)lA + off) = b;
        }
        // stage B: 256 cols x 64 k (WfcT already [col][k] bf16)
        #pragma unroll
        for (int q = 0; q < 4; ++q) {
            int idx = tid + 512 * q;
            int c = idx >> 3, k8 = idx & 7;
            uint4 v = *(const uint4*)(WfcT + (size_t)(col0 + c) * LIN + kt * 64 + k8 * 8);
            u32 off = c * 128 + ((k8 * 16) ^ ((c & 7) << 4));
            *(uint4*)((char*)lB + off) = v;
        }
        __syncthreads();
        #pragma unroll
        for (int kk = 0; kk < 2; ++kk) {
            bf16x8 af[4], bf[4];
            #pragma unroll
            for (int m = 0; m < 4; ++m) {
                int row = wr * 64 + m * 16 + lanelo;
                u32 off = row * 128 + (((u32)(kk * 64 + lanehi * 16)) ^ ((row & 7) << 4));
                af[m] = *(const bf16x8*)((char*)lA + off);
            }
            #pragma unroll
            for (int n = 0; n < 4; ++n) {
                int c = wc * 64 + n * 16 + lanelo;
                u32 off = c * 128 + (((u32)(kk * 64 + lanehi * 16)) ^ ((c & 7) << 4));
                bf[n] = *(const bf16x8*)((char*)lB + off);
            }
            #pragma unroll
            for (int m = 0; m < 4; ++m)
                #pragma unroll
                for (int n = 0; n < 4; ++n)
                    acc[m][n] = __builtin_amdgcn_mfma_f32_16x16x32_bf16(af[m], bf[n], acc[m][n], 0, 0, 0);
        }
        __syncthreads();
    }
    // epilogue: bias + relu -> bf16
    #pragma unroll
    for (int n = 0; n < 4; ++n) {
        int col = col0 + wc * 64 + n * 16 + lanelo;
        float bias = b_fc[col];
        #pragma unroll
        for (int m = 0; m < 4; ++m) {
            int rbase = row0 + wr * 64 + m * 16 + 4 * lanehi;
            #pragma unroll
            for (int r = 0; r < 4; ++r) {
                float v = acc[m][n][r] + bias;
                v = v > 0.f ? v : 0.f;
                h512[(size_t)(rbase + r) * D1 + col] = f2b(v);
            }
        }
    }
}

// ---------------- GEMM2 fused: a=tanh(h512@Wa+ba), b=sig(h512@Wb+bb), A_raw=(a*b)@Wc+bc
// Also: sortable keys, partial Z = sum exp(A_raw), partial M = sum exp(A_raw_i)*h512_i.
__global__ __launch_bounds__(512, 2)
void gemm_attn(const u16* __restrict__ h512, const u16* __restrict__ WaT,
               const u16* __restrict__ WbT, const float* __restrict__ ba,
               const float* __restrict__ bb, const float* __restrict__ Wc,
               const float* __restrict__ bc, float* __restrict__ araw,
               u32* __restrict__ uarr, float* __restrict__ Zacc, float* __restrict__ Mpart) {
    __shared__ __align__(16) u16 lA[128 * 64];
    __shared__ __align__(16) u16 lBa[256 * 64];
    __shared__ __align__(16) u16 lBb[256 * 64];
    __shared__ float rsum[128];
    __shared__ float sW[128];
    const int tid = threadIdx.x;
    const int lane = tid & 63, wid = tid >> 6;
    const int wr = wid >> 2, wc4 = wid & 3;
    const int lanelo = lane & 15, lanehi = lane >> 4;
    const int row0 = blockIdx.x * 128;

    f32x4 accA[4][4], accB[4][4];
    const f32x4 z4 = {0.f, 0.f, 0.f, 0.f};
    for (int m = 0; m < 4; ++m)
        for (int n = 0; n < 4; ++n) { accA[m][n] = z4; accB[m][n] = z4; }

    for (int kt = 0; kt < D1 / 64; ++kt) {
        #pragma unroll
        for (int q = 0; q < 2; ++q) {        // A tile: 128x64 bf16
            int idx = tid + 512 * q;
            int row = idx >> 3, k8 = idx & 7;
            uint4 v = *(const uint4*)(h512 + (size_t)(row0 + row) * D1 + kt * 64 + k8 * 8);
            *(uint4*)((char*)lA + row * 128 + ((k8 * 16) ^ ((row & 7) << 4))) = v;
        }
        #pragma unroll
        for (int q = 0; q < 4; ++q) {        // B tiles: 256x64 each
            int idx = tid + 512 * q;
            int c = idx >> 3, k8 = idx & 7;
            u32 off = c * 128 + ((k8 * 16) ^ ((c & 7) << 4));
            *(uint4*)((char*)lBa + off) = *(const uint4*)(WaT + (size_t)c * D1 + kt * 64 + k8 * 8);
            *(uint4*)((char*)lBb + off) = *(const uint4*)(WbT + (size_t)c * D1 + kt * 64 + k8 * 8);
        }
        __syncthreads();
        #pragma unroll
        for (int kk = 0; kk < 2; ++kk) {
            bf16x8 af[4], ga[4], gb[4];
            #pragma unroll
            for (int m = 0; m < 4; ++m) {
                int row = wr * 64 + m * 16 + lanelo;
                u32 off = row * 128 + (((u32)(kk * 64 + lanehi * 16)) ^ ((row & 7) << 4));
                af[m] = *(const bf16x8*)((char*)lA + off);
            }
            #pragma unroll
            for (int n = 0; n < 4; ++n) {
                int c = wc4 * 64 + n * 16 + lanelo;
                u32 off = c * 128 + (((u32)(kk * 64 + lanehi * 16)) ^ ((c & 7) << 4));
                ga[n] = *(const bf16x8*)((char*)lBa + off);
                gb[n] = *(const bf16x8*)((char*)lBb + off);
            }
            #pragma unroll
            for (int m = 0; m < 4; ++m)
                #pragma unroll
                for (int n = 0; n < 4; ++n) {
                    accA[m][n] = __builtin_amdgcn_mfma_f32_16x16x32_bf16(af[m], ga[n], accA[m][n], 0, 0, 0);
                    accB[m][n] = __builtin_amdgcn_mfma_f32_16x16x32_bf16(af[m], gb[n], accB[m][n], 0, 0, 0);
                }
        }
        __syncthreads();
    }

    if (tid < 128) rsum[tid] = 0.f;
    __syncthreads();

    // epilogue: p = tanh(a)*sigmoid(b); row-dot with Wc
    float baR[4], bbR[4], wcR[4];
    #pragma unroll
    for (int n = 0; n < 4; ++n) {
        int j = wc4 * 64 + n * 16 + lanelo;
        baR[n] = ba[j]; bbR[n] = bb[j]; wcR[n] = Wc[j];
    }
    #pragma unroll
    for (int m = 0; m < 4; ++m) {
        #pragma unroll
        for (int r = 0; r < 4; ++r) {
            float s = 0.f;
            #pragma unroll
            for (int n = 0; n < 4; ++n) {
                float av = accA[m][n][r] + baR[n];
                float bv = accB[m][n][r] + bbR[n];
                float p = tanhf(av) / (1.f + __expf(-bv) * 0.f + expf(-bv) * 1.f);
                s += p * wcR[n];
            }
            s += __shfl_xor(s, 1); s += __shfl_xor(s, 2);
            s += __shfl_xor(s, 4); s += __shfl_xor(s, 8);
            if (lanelo == 0) atomicAdd(&rsum[wr * 64 + m * 16 + 4 * lanehi + r], s);
        }
    }
    __syncthreads();

    if (tid < 128) {
        int rg = row0 + tid;
        float e = 0.f;
        if (rg < N_INST) {
            float a = rsum[tid] + bc[0];
            araw[rg] = a;
            u32 bits = __float_as_uint(a);
            uarr[rg] = (bits & 0x80000000u) ? ~bits : (bits | 0x80000000u);
            e = expf(a);                       // |a| < ~4 analytically: no max-sub needed
        }
        sW[tid] = e;
    }
    __syncthreads();
    if (tid < 128) {                           // Z partial: waves 0,1 full butterfly
        float e = sW[tid];
        for (int o = 32; o > 0; o >>= 1) e += __shfl_xor(e, o);
        if (lane == 0) atomicAdd(Zacc, e);
    }
    // M partial: re-read this block's (L2-hot) tile, one column per thread
    float accM = 0.f;
    for (int i = 0; i < 128; ++i)
        accM += sW[i] * b2f(h512[(size_t)(row0 + i) * D1 + tid]);
    atomicAdd(&Mpart[tid], accM);
}

// ---------------- radix top-64 / bottom-64 select (single block, 1024 threads)
__global__ void topk_sel(const u32* __restrict__ uarr, int* __restrict__ ids) {
    __shared__ u32 hist[256];
    __shared__ int tie[2048];
    __shared__ int s_digit, s_k, cnt, tcnt;
    const int tid = threadIdx.x;
    const int BD = 1024;

    for (int mode = 0; mode < 2; ++mode) {     // 0: kth largest, 1: kth smallest
        u32 prefix = 0; int k = TOPK;
        for (int shift = 24; shift >= 0; shift -= 8) {
            if (tid < 256) hist[tid] = 0;
            __syncthreads();
            u32 maskhi = (shift == 24) ? 0u : (0xFFFFFFFFu << (shift + 8));
            for (int i = tid; i < N_INST; i += BD) {
                u32 v = uarr[i];
                if ((v & maskhi) == prefix) atomicAdd(&hist[(v >> shift) & 255u], 1u);
            }
            __syncthreads();
            if (tid == 0) {
                int acc = 0, d;
                if (mode == 0) { for (d = 255; d >= 0; --d) { acc += (int)hist[d]; if (acc >= k) break; } }
                else           { for (d = 0; d <= 255; ++d) { acc += (int)hist[d]; if (acc >= k) break; } }
                s_digit = d; s_k = k - (acc - (int)hist[d]);
            }
            __syncthreads();
            prefix |= ((u32)s_digit) << shift;
            k = s_k;
            __syncthreads();
        }
        u32 vth = prefix;
        if (tid == 0) { cnt = 0; tcnt = 0; }
        __syncthreads();
        int* dst = ids + mode * TOPK;
        for (int i = tid; i < N_INST; i += BD) {
            u32 v = uarr[i];
            bool strict = mode == 0 ? (v > vth) : (v < vth);
            if (strict) { int p = atomicAdd(&cnt, 1); if (p < TOPK) dst[p] = i; }
            else if (v == vth) { int p = atomicAdd(&tcnt, 1); if (p < 2048) tie[p] = i; }
        }
        __syncthreads();
        if (tid == 0) {                        // fill remainder with lowest tie indices (jax tie order)
            int have = cnt < TOPK ? cnt : TOPK;
            int need = TOPK - have;
            int m = tcnt < 2048 ? tcnt : 2048;
            int last = -1;
            for (int t = 0; t < need; ++t) {
                int best = 0x7FFFFFFF;
                for (int s = 0; s < m; ++s) { int ix = tie[s]; if (ix > last && ix < best) best = ix; }
                dst[have + t] = best; last = best;
            }
        }
        __syncthreads();
    }
}

// ---------------- instance CE loss over gathered 128 rows
__global__ void inst_loss(const u16* __restrict__ h512, const int* __restrict__ ids,
                          const float* __restrict__ W_inst, const float* __restrict__ b_inst,
                          const int* __restrict__ label, float* __restrict__ out_loss) {
    __shared__ float lsum;
    const int tid = threadIdx.x;               // 256
    const int lane = tid & 63, wid = tid >> 6;
    if (tid == 0) lsum = 0.f;
    __syncthreads();
    const int lab = label[0];
    const float* W = W_inst + (size_t)lab * (D1 * 2);
    const float b0 = b_inst[lab * 2 + 0], b1 = b_inst[lab * 2 + 1];
    for (int i = 0; i < 32; ++i) {
        int r = wid * 32 + i;
        int row = ids[r];
        float s0 = 0.f, s1 = 0.f;
        for (int s = 0; s < 8; ++s) {
            int j = lane + 64 * s;
            float hv = b2f(h512[(size_t)row * D1 + j]);
            s0 += hv * W[j * 2 + 0];
            s1 += hv * W[j * 2 + 1];
        }
        for (int o = 32; o > 0; o >>= 1) { s0 += __shfl_xor(s0, o); s1 += __shfl_xor(s1, o); }
        if (lane == 0) {
            float l0 = s0 + b0, l1 = s1 + b1;
            float mx = fmaxf(l0, l1);
            float lse = mx + logf(expf(l0 - mx) + expf(l1 - mx));
            float lt = (r < TOPK) ? l1 : l0;   // first 64 -> target 1, next 64 -> target 0
            atomicAdd(&lsum, lse - lt);
        }
    }
    __syncthreads();
    if (tid == 0) out_loss[0] = lsum / 128.f;
}

// ---------------- final head: M, img gate, tab softmax gate, 561->2 classifier
__global__ void final_head(const float* __restrict__ Mpart, const float* __restrict__ Zacc,
                           const float* __restrict__ tabular, const float* __restrict__ W_img,
                           const float* __restrict__ b_img, const float* __restrict__ W_tab,
                           const float* __restrict__ b_tab, const float* __restrict__ W_cls,
                           const float* __restrict__ b_cls, float* __restrict__ d_out) {
    __shared__ float sM[512];
    __shared__ float stab[TDIM];
    __shared__ float red0[256], red1[256];
    __shared__ float simg;
    const int tid = threadIdx.x;               // 256
    float invZ = 1.f / Zacc[0];
    sM[tid] = Mpart[tid] * invZ;
    sM[tid + 256] = Mpart[tid + 256] * invZ;
    red0[tid] = sM[tid] * W_img[tid] + sM[tid + 256] * W_img[tid + 256];
    __syncthreads();
    for (int o = 128; o > 0; o >>= 1) { if (tid < o) red0[tid] += red0[tid + o]; __syncthreads(); }
    if (tid == 0) simg = 1.f / (1.f + expf(-(red0[0] + b_img[0])));
    if (tid < TDIM) {
        float t = b_tab[tid];
        for (int kx = 0; kx < TDIM; ++kx) t += tabular[kx] * W_tab[kx * TDIM + tid];
        stab[tid] = t;
    }
    __syncthreads();
    if (tid == 0) {
        float mx = stab[0];
        for (int o = 1; o < TDIM; ++o) mx = fmaxf(mx, stab[o]);
        float ss = 0.f;
        for (int o = 0; o < TDIM; ++o) { float e = expf(stab[o] - mx); stab[o] = e; ss += e; }
        for (int o = 0; o < TDIM; ++o) stab[o] = (stab[o] / ss) * tabular[o];
    }
    __syncthreads();
    float img = simg;
    float a0 = 0.f, a1 = 0.f;
    for (int j = tid; j < D1 + TDIM; j += 256) {
        float w = (j < D1) ? img * sM[j] : stab[j - D1];
        a0 += w * W_cls[j * 2 + 0];
        a1 += w * W_cls[j * 2 + 1];
    }
    red0[tid] = a0; red1[tid] = a1;
    __syncthreads();
    for (int o = 128; o > 0; o >>= 1) {
        if (tid < o) { red0[tid] += red0[tid + o]; red1[tid] += red1[tid + o]; }
        __syncthreads();
    }
    if (tid == 0) {
        float l0 = red0[0] + b_cls[0];
        float l1 = red1[0] + b_cls[1];
        d_out[0] = l0; d_out[1] = l1;
        float mx = fmaxf(l0, l1);
        float e0 = expf(l0 - mx), e1 = expf(l1 - mx);
        d_out[2] = e0 / (e0 + e1);
        d_out[3] = e1 / (e0 + e1);
        d_out[4] = (l1 > l0) ? 1.f : 0.f;      // argmax, ties -> 0
    }
}

extern "C" void kernel_launch(void* const* d_in, const int* in_sizes, int n_in,
                              void* d_out, int out_size, void* d_ws, size_t ws_size,
                              hipStream_t stream) {
    const float* h       = (const float*)d_in[0];
    const float* tabular = (const float*)d_in[1];
    const int*   label   = (const int*)d_in[2];
    const float* W_fc    = (const float*)d_in[3];
    const float* b_fc    = (const float*)d_in[4];
    const float* Wa      = (const float*)d_in[5];
    const float* ba      = (const float*)d_in[6];
    const float* Wb      = (const float*)d_in[7];
    const float* bb      = (const float*)d_in[8];
    const float* Wc      = (const float*)d_in[9];
    const float* bc      = (const float*)d_in[10];
    const float* W_inst  = (const float*)d_in[11];
    const float* b_inst  = (const float*)d_in[12];
    const float* W_img   = (const float*)d_in[13];
    const float* b_img   = (const float*)d_in[14];
    const float* W_tab   = (const float*)d_in[15];
    const float* b_tab   = (const float*)d_in[16];
    const float* W_cls   = (const float*)d_in[17];
    const float* b_cls   = (const float*)d_in[18];
    float* out = (float*)d_out;

    // workspace layout
    u16* h512 = (u16*)d_ws;                          // NPAD x 512 bf16      (51.2 MB)
    u16* WfcT = h512 + (size_t)NPAD * D1;            // 512 x 1024 bf16      (1 MB)
    u16* WaT  = WfcT + (size_t)D1 * LIN;             // 256 x 512 bf16
    u16* WbT  = WaT + (size_t)D2 * D1;
    u32* uarr = (u32*)(WbT + (size_t)D2 * D1);       // NPAD sortable keys
    float* accum = (float*)(uarr + NPAD);            // [0]=Z, [8..520)=Mpart
    float* Zacc  = accum;
    float* Mpart = accum + 8;
    int* ids = (int*)(accum + 8 + D1);               // 128 selected indices

    hipMemsetAsync(accum, 0, (8 + D1) * sizeof(float), stream);
    pack_weights<<<dim3((D1 * LIN + D2 * D1 + 255) / 256), dim3(256), 0, stream>>>(
        W_fc, Wa, Wb, WfcT, WaT, WbT);
    gemm_fc<<<dim3(2, NPAD / 128), dim3(512), 0, stream>>>(h, WfcT, b_fc, h512);
    gemm_attn<<<dim3(NPAD / 128), dim3(512), 0, stream>>>(
        h512, WaT, WbT, ba, bb, Wc, bc, out + 5, uarr, Zacc, Mpart);
    topk_sel<<<dim3(1), dim3(1024), 0, stream>>>(uarr, ids);
    inst_loss<<<dim3(1), dim3(256), 0, stream>>>(h512, ids, W_inst, b_inst, label, out + 50005);
    final_head<<<dim3(1), dim3(256), 0, stream>>>(
        Mpart, Zacc, tabular, W_img, b_img, W_tab, b_tab, W_cls, b_cls, out);
}